// Round 3
// baseline (672.879 us; speedup 1.0000x reference)
//
#include <hip/hip_runtime.h>
#include <cmath>

#ifndef M_PI
#define M_PI 3.14159265358979323846
#endif

#define NH 32
#define NW 32
#define NP 64
#define NU 64
#define NL 32
#define NB 8
#define NIMG 256
#define NIMG_TOT 264
#define HWN 1024
#define IMG_STRIDE 65536          // float2 elements per image region

typedef unsigned short u16;
typedef unsigned int u32;
typedef __bf16 bf16x8 __attribute__((ext_vector_type(8)));
typedef float f32x4 __attribute__((ext_vector_type(4)));

__device__ __forceinline__ u16 f2bf(float f) {
  unsigned u = __float_as_uint(f);
  u += 0x7fffu + ((u >> 16) & 1u);   // RNE
  return (u16)(u >> 16);
}
__device__ __forceinline__ float bf2f(u16 h) {
  return __uint_as_float(((unsigned)h) << 16);
}

// ---------------------------------------------------------------------------
// Layout: XBUF is pc-major per image:
//   float2 X[img][pc 32][pix 1024][pp 2]
// Packed convCD input (written in-place by k_dst_inv, same window):
//   u32 XP[img][pc][pix][{re_pp0, re_pp1, im_pp0, im_pp1}]  (hi | lo<<16)
// Conv kernels are 8-wave (512 threads) — n-tile split across waves —
// to lift occupancy past the LDS-limited 12 waves/CU
// (rocprof r1: Occupancy 30%, MfmaUtil 38%).
// ---------------------------------------------------------------------------

// ---------------------------------------------------------------------------
// K0: S matrix (32x32 DST-I, real symmetric involutive) + kv from softmax
// ---------------------------------------------------------------------------
__global__ void k_setup(const float* __restrict__ values, float* __restrict__ S,
                        float* __restrict__ kv) {
  int t = threadIdx.x;
  int i = t >> 5, j = t & 31;
  double s = sin(M_PI * (double)((i + 1) * (j + 1)) / 33.0) / sqrt(16.5);
  S[t] = (float)s;
  if (t < NP) {
    float v0 = values[t * 4 + 0], v1 = values[t * 4 + 1];
    float v2 = values[t * 4 + 2], v3 = values[t * 4 + 3];
    float m = fmaxf(fmaxf(v0, v1), fmaxf(v2, v3));
    float e0 = expf(v0 - m), e1 = expf(v1 - m), e2 = expf(v2 - m), e3 = expf(v3 - m);
    float inv = 4.0f / (e0 + e1 + e2 + e3);
    float xk = e0 * inv, yk = e1 * inv, zk = e2 * inv, wk = e3 * inv;
    kv[t * 4 + 0] = (xk + yk - 2.0f) * 0.25f;
    kv[t * 4 + 1] = (xk + zk - 2.0f) * 0.25f;
    kv[t * 4 + 2] = (xk + wk - 2.0f) * 0.125f;
    kv[t * 4 + 3] = 0.f;
  }
}

// ---------------------------------------------------------------------------
// K1: A_bar, B_coeff in double; pc-major layout shared with k_scan.
// ---------------------------------------------------------------------------
__global__ void k_coeff(const float* __restrict__ Lre, const float* __restrict__ Lim,
                        const float* __restrict__ log_step, const float* __restrict__ kv,
                        float2* __restrict__ A, float2* __restrict__ Bc) {
  int tid = blockIdx.x * blockDim.x + threadIdx.x;
  int n = tid >> 6, p = tid & 63;
  int h = n >> 5, w = n & 31;
  double ch = 2.0 * cos(M_PI * (double)(h + 1) / 33.0);
  double cw = 2.0 * cos(M_PI * (double)(w + 1) / 33.0);
  double Dv = (double)kv[p * 4 + 0] * cw + (double)kv[p * 4 + 1] * ch +
              (double)kv[p * 4 + 2] * ch * cw + 1.0;
  double lr = fmin((double)Lre[p], -0.0001);
  double li = (double)Lim[p];
  double tr = lr * Dv, ti = li * Dv;
  double st = exp((double)log_step[p]);
  double zr = tr * st, zi = ti * st;
  double ea = exp(zr);
  double Ar = ea * cos(zi), Ai = ea * sin(zi);
  double d = tr * tr + ti * ti;
  double br = ((Ar - 1.0) * tr + Ai * ti) / d;
  double bi = (Ai * tr - (Ar - 1.0) * ti) / d;
  size_t o = (size_t)(p >> 1) * 2048 + (size_t)n * 2 + (p & 1);
  A[o]  = make_float2((float)Ar, (float)Ai);
  Bc[o] = make_float2((float)br, (float)bi);
}

// ---------------------------------------------------------------------------
// K1b: pack conv weights into MFMA-fragment order, split bf16 hi/lo.
// ---------------------------------------------------------------------------
#define NB_PACK (18 * 8 * 64 * 8)    // 73728
#define NC_PACK (54 * 4 * 64 * 8)    // 110592
__global__ __launch_bounds__(256) void k_pack(
    const float* __restrict__ Br, const float* __restrict__ Bi,
    const float* __restrict__ Cr, const float* __restrict__ Ci,
    const float* __restrict__ Dk,
    u16* __restrict__ WBhi, u16* __restrict__ WBlo,
    u16* __restrict__ WChi, u16* __restrict__ WClo) {
  int tid = blockIdx.x * 256 + threadIdx.x;
  if (tid < NB_PACK) {
    int j = tid & 7, lane = (tid >> 3) & 63, nt = (tid >> 9) & 7, kc = tid >> 12;
    int k = kc * 32 + ((lane >> 4) << 3) + j;
    int n = nt * 16 + (lane & 15);
    int tap = k >> 6, c = k & 63;
    float w = (n < 64) ? Br[(tap * 64 + c) * 64 + n]
                       : Bi[(tap * 64 + c) * 64 + (n - 64)];
    u16 hi = f2bf(w);
    WBhi[tid] = hi;
    WBlo[tid] = f2bf(w - bf2f(hi));
  } else {
    int t2 = tid - NB_PACK;
    if (t2 < NC_PACK) {
      int j = t2 & 7, lane = (t2 >> 3) & 63, nt = (t2 >> 9) & 3, kc = t2 >> 11;
      int k = kc * 32 + ((lane >> 4) << 3) + j;     // 0..1727
      int n = nt * 16 + (lane & 15);                 // 0..63
      int s = k / 576, rem = k % 576;
      int tap = rem >> 6, c = rem & 63;
      int widx = (tap * 64 + c) * 64 + n;
      float w = (s == 0) ? 2.f * Cr[widx] : (s == 1) ? -2.f * Ci[widx] : Dk[widx];
      u16 hi = f2bf(w);
      WChi[t2] = hi;
      WClo[t2] = f2bf(w - bf2f(hi));
    }
  }
}

// ---------------------------------------------------------------------------
// K2: convB via MFMA. 8 waves/block: mgrp = wv>>2 (row pair), ng = wv&3;
//     each wave owns nt = ng (real, n<64) and nt = ng+4 (imag, n>=64).
// ---------------------------------------------------------------------------
__global__ __launch_bounds__(512, 4) void k_convB_mfma(
    const float* __restrict__ u, const float* __restrict__ x0,
    const u16* __restrict__ WBhi, const u16* __restrict__ WBlo,
    float2* __restrict__ XBUF) {
  __shared__ u16 lhs[6 * 34 * 64];
  __shared__ u16 lls[6 * 34 * 64];
  int img = blockIdx.x, h0 = blockIdx.y * 4;
  int t = threadIdx.x;
  const float* src = (img < NIMG) ? (u + (size_t)img * HWN * NU)
                                  : (x0 + (size_t)(img - NIMG) * HWN * NU);
  for (int idx = t; idx < 6 * 34 * 16; idx += 512) {
    int c4 = idx & 15, rem = idx >> 4, w = rem % 34, r = rem / 34;
    int hh = h0 - 1 + r, wg = w - 1;
    float4 v = make_float4(0.f, 0.f, 0.f, 0.f);
    if (hh >= 0 && hh < NH && wg >= 0 && wg < NW)
      v = *(const float4*)(src + (hh * 32 + wg) * 64 + c4 * 4);
    u16 a0 = f2bf(v.x), a1 = f2bf(v.y), a2 = f2bf(v.z), a3 = f2bf(v.w);
    u16 b0 = f2bf(v.x - bf2f(a0)), b1 = f2bf(v.y - bf2f(a1));
    u16 b2 = f2bf(v.z - bf2f(a2)), b3 = f2bf(v.w - bf2f(a3));
    int a = (r * 34 + w) * 64 + (((c4 >> 1) ^ (w & 7)) << 3) + ((c4 & 1) << 2);
    *(ushort4*)&lhs[a] = make_ushort4(a0, a1, a2, a3);
    *(ushort4*)&lls[a] = make_ushort4(b0, b1, b2, b3);
  }
  __syncthreads();
  int lane = t & 63, wv = t >> 6;
  int mgrp = wv >> 2, ng = wv & 3;
  int l15 = lane & 15, l4 = lane >> 4;
  f32x4 acc[4][2];
#pragma unroll
  for (int i = 0; i < 4; i++)
#pragma unroll
    for (int q = 0; q < 2; q++) acc[i][q] = (f32x4){0.f, 0.f, 0.f, 0.f};

  for (int tap = 0; tap < 9; tap++) {
    int kh = tap / 3, kw = tap - kh * 3;
#pragma unroll
    for (int cc = 0; cc < 2; cc++) {
      int kc = tap * 2 + cc;
      bf16x8 wh[2], wl[2];
#pragma unroll
      for (int q = 0; q < 2; q++) {
        int nt = ng + q * 4;
        size_t woff = ((size_t)((kc * 8 + nt) * 64 + lane)) * 8;
        wh[q] = *(const bf16x8*)&WBhi[woff];
        wl[q] = *(const bf16x8*)&WBlo[woff];
      }
#pragma unroll
      for (int mti = 0; mti < 4; mti++) {
        int row = mgrp * 2 + (mti >> 1);
        int wt = (mti & 1) * 16 + l15 + kw;
        int off = ((row + kh) * 34 + wt) * 64 + (((cc * 4 + l4) ^ (wt & 7)) << 3);
        bf16x8 ah = *(const bf16x8*)&lhs[off];
        bf16x8 al = *(const bf16x8*)&lls[off];
#pragma unroll
        for (int q = 0; q < 2; q++) {
          f32x4 c = acc[mti][q];
          c = __builtin_amdgcn_mfma_f32_16x16x32_bf16(ah, wh[q], c, 0, 0, 0);
          c = __builtin_amdgcn_mfma_f32_16x16x32_bf16(ah, wl[q], c, 0, 0, 0);
          c = __builtin_amdgcn_mfma_f32_16x16x32_bf16(al, wh[q], c, 0, 0, 0);
          acc[mti][q] = c;
        }
      }
    }
  }
  float2* dst = XBUF + (size_t)img * IMG_STRIDE;
  int p = ng * 16 + l15;
  int pc = p >> 1, pp = p & 1;
#pragma unroll
  for (int mti = 0; mti < 4; mti++) {
    int h = h0 + mgrp * 2 + (mti >> 1);
#pragma unroll
    for (int reg = 0; reg < 4; reg++) {
      int wpix = (mti & 1) * 16 + l4 * 4 + reg;
      float re = acc[mti][0][reg];
      float im = acc[mti][1][reg];
      int m = (h + wpix + 2) & 3;
      float2 o;
      if (m == 0)      o = make_float2( re,  im);
      else if (m == 1) o = make_float2( im, -re);
      else if (m == 2) o = make_float2(-re, -im);
      else             o = make_float2(-im,  re);
      dst[(size_t)pc * 2048 + (h * 32 + wpix) * 2 + pp] = o;
    }
  }
}

// ---------------------------------------------------------------------------
// K3: forward DST IN-PLACE, register-tiled. Block = (img, pc 0..31).
//     Contiguous 16 KB global window per block.
// ---------------------------------------------------------------------------
__global__ __launch_bounds__(256) void k_dst_fwd(float2* __restrict__ XBUF,
                                                 const float* __restrict__ S) {
  int img = blockIdx.x, pc = blockIdx.y;
  __shared__ float tin[32 * 32 * 4];   // [d1][d2][pp*2+ri]
  __shared__ float t1 [32 * 32 * 4];   // [o1][d2 ^ (ag&7)][ppri]
  int t = threadIdx.x;
  float2* base = XBUF + (size_t)img * IMG_STRIDE + (size_t)pc * 2048;
  for (int n = t; n < 1024; n += 256) {
    float4 v = *(const float4*)&base[n * 2];
    *(float4*)&tin[n * 4] = v;
  }
  __syncthreads();
  {  // stage 1
    int w = t & 31, ag = t >> 5;
    f32x4 acc[4];
#pragma unroll
    for (int i = 0; i < 4; i++) acc[i] = (f32x4){0.f, 0.f, 0.f, 0.f};
#pragma unroll 8
    for (int hh = 0; hh < 32; hh++) {
      f32x4 v = *(const f32x4*)&tin[(hh * 32 + w) * 4];
      f32x4 s4 = *(const f32x4*)&S[hh * 32 + ag * 4];
#pragma unroll
      for (int i = 0; i < 4; i++) acc[i] += s4[i] * v;
    }
    int wp = w ^ (ag & 7);
#pragma unroll
    for (int i = 0; i < 4; i++)
      *(f32x4*)&t1[((ag * 4 + i) * 32 + wp) * 4] = acc[i];
  }
  __syncthreads();
  {  // stage 2
    int pp = t & 1, cg = (t >> 1) & 15, ag = t >> 5;
    float acc[4][2][2];
#pragma unroll
    for (int i = 0; i < 4; i++)
#pragma unroll
      for (int j = 0; j < 2; j++) acc[i][j][0] = acc[i][j][1] = 0.f;
#pragma unroll 8
    for (int w = 0; w < 32; w++) {
      int wp = w ^ (ag & 7);
      float2 sc = *(const float2*)&S[w * 32 + cg * 2];
#pragma unroll
      for (int i = 0; i < 4; i++) {
        float2 tv = *(const float2*)&t1[((ag * 4 + i) * 32 + wp) * 4 + pp * 2];
        acc[i][0][0] = fmaf(tv.x, sc.x, acc[i][0][0]);
        acc[i][0][1] = fmaf(tv.y, sc.x, acc[i][0][1]);
        acc[i][1][0] = fmaf(tv.x, sc.y, acc[i][1][0]);
        acc[i][1][1] = fmaf(tv.y, sc.y, acc[i][1][1]);
      }
    }
#pragma unroll
    for (int i = 0; i < 4; i++)
#pragma unroll
      for (int j = 0; j < 2; j++) {
        int n = (ag * 4 + i) * 32 + cg * 2 + j;
        base[n * 2 + pp] = make_float2(acc[i][j][0], acc[i][j][1]);
      }
  }
}

// ---------------------------------------------------------------------------
// K4: scan over l. Linear-offset streaming in the pc-major layout.
// ---------------------------------------------------------------------------
__global__ __launch_bounds__(256) void k_scan(const float2* __restrict__ A,
                                              const float2* __restrict__ Bc,
                                              float2* __restrict__ X) {
  int gx = blockIdx.x;
  int b = gx >> 8, sl = gx & 255;
  int t = threadIdx.x;
  size_t off = (size_t)sl * 256 + t;
  float2 Av = A[off];
  float2 Bv = Bc[off];
  float2 v0 = X[(size_t)(NIMG + b) * IMG_STRIDE + off];
  float2 x;
  x.x = Bv.x * v0.x - Bv.y * v0.y;
  x.y = Bv.x * v0.y + Bv.y * v0.x;
  for (int l = 0; l < NL; l++) {
    size_t idx = (size_t)(l * NB + b) * IMG_STRIDE + off;
    float2 v = X[idx];
    float vr = Bv.x * v.x - Bv.y * v.y;
    float vi = Bv.x * v.y + Bv.y * v.x;
    float2 nx;
    nx.x = Av.x * x.x - Av.y * x.y + vr;
    nx.y = Av.x * x.y + Av.y * x.x + vi;
    x = nx;
    X[idx] = x;
  }
}

// ---------------------------------------------------------------------------
// K5: inverse DST IN-PLACE, register-tiled, + phase + bf16-split pack.
//     Reads contiguous 16 KB; writes the SAME 16 KB window as packed u32:
//     XP[pc][pix][{re_pp0, re_pp1, im_pp0, im_pp1}], each hi | lo<<16.
// ---------------------------------------------------------------------------
__global__ __launch_bounds__(256) void k_dst_inv(float2* __restrict__ XBUF,
                                                 const float* __restrict__ S) {
  int img = blockIdx.x, pc = blockIdx.y;
  __shared__ float tin[32 * 32 * 4];   // [a][c][ppri]
  __shared__ float t1 [32 * 32 * 4];   // [h][c ^ (ag&7)][ppri]
  int t = threadIdx.x;
  float2* base = XBUF + (size_t)img * IMG_STRIDE + (size_t)pc * 2048;
  for (int n = t; n < 1024; n += 256) {
    float4 v = *(const float4*)&base[n * 2];
    *(float4*)&tin[n * 4] = v;
  }
  __syncthreads();
  {  // stage 1: t1[h][c] = sum_a S[h][a] * xin[a][c]
    int c = t & 31, ag = t >> 5;
    f32x4 acc[4];
#pragma unroll
    for (int i = 0; i < 4; i++) acc[i] = (f32x4){0.f, 0.f, 0.f, 0.f};
#pragma unroll 8
    for (int a = 0; a < 32; a++) {
      f32x4 v = *(const f32x4*)&tin[(a * 32 + c) * 4];
      f32x4 s4 = *(const f32x4*)&S[a * 32 + ag * 4];
#pragma unroll
      for (int i = 0; i < 4; i++) acc[i] += s4[i] * v;
    }
    int cp = c ^ (ag & 7);
#pragma unroll
    for (int i = 0; i < 4; i++)
      *(f32x4*)&t1[((ag * 4 + i) * 32 + cp) * 4] = acc[i];
  }
  __syncthreads();
  {  // stage 2: out[h][w] = sum_c S[w][c] * t1[h][c]; phase; split-pack
    int pp = t & 1, wg = (t >> 1) & 15, ag = t >> 5;
    float acc[4][2][2];
#pragma unroll
    for (int i = 0; i < 4; i++)
#pragma unroll
      for (int j = 0; j < 2; j++) acc[i][j][0] = acc[i][j][1] = 0.f;
#pragma unroll 8
    for (int c = 0; c < 32; c++) {
      int cp = c ^ (ag & 7);
      float2 sc = *(const float2*)&S[c * 32 + wg * 2];
#pragma unroll
      for (int i = 0; i < 4; i++) {
        float2 tv = *(const float2*)&t1[((ag * 4 + i) * 32 + cp) * 4 + pp * 2];
        acc[i][0][0] = fmaf(tv.x, sc.x, acc[i][0][0]);
        acc[i][0][1] = fmaf(tv.y, sc.x, acc[i][0][1]);
        acc[i][1][0] = fmaf(tv.x, sc.y, acc[i][1][0]);
        acc[i][1][1] = fmaf(tv.y, sc.y, acc[i][1][1]);
      }
    }
    u32* gw = (u32*)(XBUF + (size_t)img * IMG_STRIDE) + (size_t)pc * 4096;
#pragma unroll
    for (int i = 0; i < 4; i++)
#pragma unroll
      for (int j = 0; j < 2; j++) {
        int h = ag * 4 + i, wpx = wg * 2 + j;
        float re = acc[i][j][0], im = acc[i][j][1];
        int m = (h + wpx + 2) & 3;
        float2 o;
        if (m == 0)      o = make_float2( re,  im);
        else if (m == 1) o = make_float2(-im,  re);
        else if (m == 2) o = make_float2(-re, -im);
        else             o = make_float2( im, -re);
        u16 hr = f2bf(o.x), lr = f2bf(o.x - bf2f(hr));
        u16 hm = f2bf(o.y), lm = f2bf(o.y - bf2f(hm));
        int pix = h * 32 + wpx;
        gw[pix * 4 + pp]     = (u32)hr | ((u32)lr << 16);   // comp 0 (re)
        gw[pix * 4 + 2 + pp] = (u32)hm | ((u32)lm << 16);   // comp 1 (im)
      }
  }
}

// ---------------------------------------------------------------------------
// K6: convCD via MFMA + gelu. 8 waves/block: mgrp = wv>>2, ng = wv&3;
//     each wave owns one 16-wide output-channel tile (nt = ng).
// ---------------------------------------------------------------------------
__global__ __launch_bounds__(512, 4) void k_convCD_mfma(
    const u32* __restrict__ XP,      // XBUF viewed as packed slots
    const float* __restrict__ u,
    const u16* __restrict__ WChi, const u16* __restrict__ WClo,
    float* __restrict__ out) {
  __shared__ u16 lhs[6 * 34 * 64];
  __shared__ u16 lls[6 * 34 * 64];
  int img = blockIdx.x, h0 = blockIdx.y * 4;
  int t = threadIdx.x;
  int lane = t & 63, wv = t >> 6;
  int mgrp = wv >> 2, ng = wv & 3;
  int l15 = lane & 15, l4 = lane >> 4;
  const u32* xim = XP + (size_t)img * IMG_STRIDE * 2;   // 131072 u32 per image
  const float* uim = u + (size_t)img * HWN * NU;
  f32x4 acc[4];
#pragma unroll
  for (int i = 0; i < 4; i++) acc[i] = (f32x4){0.f, 0.f, 0.f, 0.f};

  for (int s = 0; s < 3; s++) {
    __syncthreads();
    if (s < 2) {
      // comp s: per (pc, pixel) load uint2 {pp0, pp1} at [pc][pix][s*2..]
      for (int idx = t; idx < 6 * 34 * 32; idx += 512) {
        int w = idx % 34;
        int rem = idx / 34;
        int r = rem % 6;
        int pc = rem / 6;
        int hh = h0 - 1 + r, wg = w - 1;
        uint2 d = make_uint2(0u, 0u);
        if (hh >= 0 && hh < NH && wg >= 0 && wg < NW)
          d = *(const uint2*)(xim + (size_t)pc * 4096 + (hh * 32 + wg) * 4 + s * 2);
        u32 hip = (d.x & 0xffffu) | (d.y << 16);
        u32 lop = (d.x >> 16) | (d.y & 0xffff0000u);
        int c = pc * 2;                               // channel pair c, c+1
        int a = (r * 34 + w) * 64 + (((c >> 3) ^ (w & 7)) << 3) + (c & 7);
        *(u32*)&lhs[a] = hip;
        *(u32*)&lls[a] = lop;
      }
    } else {
      for (int idx = t; idx < 6 * 34 * 16; idx += 512) {
        int c4 = idx & 15, rem = idx >> 4, w = rem % 34, r = rem / 34;
        int hh = h0 - 1 + r, wg = w - 1;
        float4 v = make_float4(0.f, 0.f, 0.f, 0.f);
        if (hh >= 0 && hh < NH && wg >= 0 && wg < NW)
          v = *(const float4*)(uim + (hh * 32 + wg) * 64 + c4 * 4);
        u16 a0 = f2bf(v.x), a1 = f2bf(v.y), a2 = f2bf(v.z), a3 = f2bf(v.w);
        u16 b0 = f2bf(v.x - bf2f(a0)), b1 = f2bf(v.y - bf2f(a1));
        u16 b2 = f2bf(v.z - bf2f(a2)), b3 = f2bf(v.w - bf2f(a3));
        int a = (r * 34 + w) * 64 + (((c4 >> 1) ^ (w & 7)) << 3) + ((c4 & 1) << 2);
        *(ushort4*)&lhs[a] = make_ushort4(a0, a1, a2, a3);
        *(ushort4*)&lls[a] = make_ushort4(b0, b1, b2, b3);
      }
    }
    __syncthreads();
    for (int tap = 0; tap < 9; tap++) {
      int kh = tap / 3, kw = tap - kh * 3;
#pragma unroll
      for (int cc = 0; cc < 2; cc++) {
        int kc = (s * 9 + tap) * 2 + cc;
        size_t woff = ((size_t)((kc * 4 + ng) * 64 + lane)) * 8;
        bf16x8 wh = *(const bf16x8*)&WChi[woff];
        bf16x8 wl = *(const bf16x8*)&WClo[woff];
#pragma unroll
        for (int mti = 0; mti < 4; mti++) {
          int row = mgrp * 2 + (mti >> 1);
          int wt = (mti & 1) * 16 + l15 + kw;
          int off = ((row + kh) * 34 + wt) * 64 + (((cc * 4 + l4) ^ (wt & 7)) << 3);
          bf16x8 ah = *(const bf16x8*)&lhs[off];
          bf16x8 al = *(const bf16x8*)&lls[off];
          f32x4 c = acc[mti];
          c = __builtin_amdgcn_mfma_f32_16x16x32_bf16(ah, wh, c, 0, 0, 0);
          c = __builtin_amdgcn_mfma_f32_16x16x32_bf16(ah, wl, c, 0, 0, 0);
          c = __builtin_amdgcn_mfma_f32_16x16x32_bf16(al, wh, c, 0, 0, 0);
          acc[mti] = c;
        }
      }
    }
  }
  float* dst = out + (size_t)img * HWN * NU;
  int un = ng * 16 + l15;
#pragma unroll
  for (int mti = 0; mti < 4; mti++) {
    int h = h0 + mgrp * 2 + (mti >> 1);
#pragma unroll
    for (int reg = 0; reg < 4; reg++) {
      int wpix = (mti & 1) * 16 + l4 * 4 + reg;
      float x = acc[mti][reg];
      float z = 0.7978845608028654f * (x + 0.044715f * x * x * x);
      float e = __expf(2.f * z);
      float th = 1.f - 2.f / (e + 1.f);
      dst[(h * 32 + wpix) * 64 + un] = 0.5f * x * (1.f + th);
    }
  }
}

// ---------------------------------------------------------------------------
extern "C" void kernel_launch(void* const* d_in, const int* in_sizes, int n_in,
                              void* d_out, int out_size, void* d_ws, size_t ws_size,
                              hipStream_t stream) {
  const float* u        = (const float*)d_in[0];
  const float* x0       = (const float*)d_in[1];
  const float* Lre      = (const float*)d_in[2];
  const float* Lim      = (const float*)d_in[3];
  const float* values   = (const float*)d_in[4];
  const float* log_step = (const float*)d_in[5];
  const float* Br       = (const float*)d_in[6];
  const float* Bi       = (const float*)d_in[7];
  const float* Cr       = (const float*)d_in[8];
  const float* Ci       = (const float*)d_in[9];
  const float* Dk       = (const float*)d_in[10];
  float* out = (float*)d_out;

  char* ws = (char*)d_ws;
  float*  S    = (float*)ws;                       ws += 4096;
  float*  kv   = (float*)ws;                       ws += 4096;
  float2* A    = (float2*)ws;                      ws += 524288;
  float2* Bc   = (float2*)ws;                      ws += 524288;
  u16*    WBhi = (u16*)ws;                         ws += NB_PACK * 2;
  u16*    WBlo = (u16*)ws;                         ws += NB_PACK * 2;
  u16*    WChi = (u16*)ws;                         ws += NC_PACK * 2;
  u16*    WClo = (u16*)ws;                         ws += NC_PACK * 2;
  float2* XBUF = (float2*)ws;

  hipLaunchKernelGGL(k_setup,      dim3(1),            dim3(1024), 0, stream, values, S, kv);
  hipLaunchKernelGGL(k_coeff,      dim3(256),          dim3(256),  0, stream, Lre, Lim, log_step, kv, A, Bc);
  hipLaunchKernelGGL(k_pack,       dim3(720),          dim3(256),  0, stream, Br, Bi, Cr, Ci, Dk, WBhi, WBlo, WChi, WClo);
  hipLaunchKernelGGL(k_convB_mfma, dim3(NIMG_TOT, 8),  dim3(512),  0, stream, u, x0, WBhi, WBlo, XBUF);
  hipLaunchKernelGGL(k_dst_fwd,    dim3(NIMG_TOT, 32), dim3(256),  0, stream, XBUF, S);
  hipLaunchKernelGGL(k_scan,       dim3(2048),         dim3(256),  0, stream, A, Bc, XBUF);
  hipLaunchKernelGGL(k_dst_inv,    dim3(NIMG, 32),     dim3(256),  0, stream, XBUF, S);
  hipLaunchKernelGGL(k_convCD_mfma,dim3(NIMG, 8),      dim3(512),  0, stream, (const u32*)XBUF, u, WChi, WClo, out);
}

// Round 4
// 653.788 us; speedup vs baseline: 1.0292x; 1.0292x over previous
//
#include <hip/hip_runtime.h>
#include <cmath>

#ifndef M_PI
#define M_PI 3.14159265358979323846
#endif

#define NH 32
#define NW 32
#define NP 64
#define NU 64
#define NL 32
#define NB 8
#define NIMG 256
#define NIMG_TOT 264
#define HWN 1024
#define IMG_STRIDE 65536          // float2 elements per image region

typedef unsigned short u16;
typedef unsigned int u32;
typedef __bf16 bf16x8 __attribute__((ext_vector_type(8)));
typedef float f32x4 __attribute__((ext_vector_type(4)));

__device__ __forceinline__ u16 f2bf(float f) {
  unsigned u = __float_as_uint(f);
  u += 0x7fffu + ((u >> 16) & 1u);   // RNE
  return (u16)(u >> 16);
}
__device__ __forceinline__ float bf2f(u16 h) {
  return __uint_as_float(((unsigned)h) << 16);
}

// ---------------------------------------------------------------------------
// Layout: XBUF is pc-major per image:
//   float2 X[img][pc 32][pix 1024][pp 2]
// Packed convCD input (written in-place by k_dst_inv, same window):
//   u32 XP[img][pc][pix][{re_pp0, re_pp1, im_pp0, im_pp1}]  (hi | lo<<16)
// This round: conv kernels back to 4-wave (8-wave doubled LDS-read traffic
// and regressed). Staging loops rewritten shift-only (no div/mod) with the
// always-zero halo columns (w=0,33) written ONCE per block instead of per
// phase — targets VALUBusy 45% (top pipe, > MFMA floor).
// ---------------------------------------------------------------------------

// ---------------------------------------------------------------------------
// K0: S matrix (32x32 DST-I, real symmetric involutive) + kv from softmax
// ---------------------------------------------------------------------------
__global__ void k_setup(const float* __restrict__ values, float* __restrict__ S,
                        float* __restrict__ kv) {
  int t = threadIdx.x;
  int i = t >> 5, j = t & 31;
  double s = sin(M_PI * (double)((i + 1) * (j + 1)) / 33.0) / sqrt(16.5);
  S[t] = (float)s;
  if (t < NP) {
    float v0 = values[t * 4 + 0], v1 = values[t * 4 + 1];
    float v2 = values[t * 4 + 2], v3 = values[t * 4 + 3];
    float m = fmaxf(fmaxf(v0, v1), fmaxf(v2, v3));
    float e0 = expf(v0 - m), e1 = expf(v1 - m), e2 = expf(v2 - m), e3 = expf(v3 - m);
    float inv = 4.0f / (e0 + e1 + e2 + e3);
    float xk = e0 * inv, yk = e1 * inv, zk = e2 * inv, wk = e3 * inv;
    kv[t * 4 + 0] = (xk + yk - 2.0f) * 0.25f;
    kv[t * 4 + 1] = (xk + zk - 2.0f) * 0.25f;
    kv[t * 4 + 2] = (xk + wk - 2.0f) * 0.125f;
    kv[t * 4 + 3] = 0.f;
  }
}

// ---------------------------------------------------------------------------
// K1: A_bar, B_coeff in double; pc-major layout shared with k_scan.
// ---------------------------------------------------------------------------
__global__ void k_coeff(const float* __restrict__ Lre, const float* __restrict__ Lim,
                        const float* __restrict__ log_step, const float* __restrict__ kv,
                        float2* __restrict__ A, float2* __restrict__ Bc) {
  int tid = blockIdx.x * blockDim.x + threadIdx.x;
  int n = tid >> 6, p = tid & 63;
  int h = n >> 5, w = n & 31;
  double ch = 2.0 * cos(M_PI * (double)(h + 1) / 33.0);
  double cw = 2.0 * cos(M_PI * (double)(w + 1) / 33.0);
  double Dv = (double)kv[p * 4 + 0] * cw + (double)kv[p * 4 + 1] * ch +
              (double)kv[p * 4 + 2] * ch * cw + 1.0;
  double lr = fmin((double)Lre[p], -0.0001);
  double li = (double)Lim[p];
  double tr = lr * Dv, ti = li * Dv;
  double st = exp((double)log_step[p]);
  double zr = tr * st, zi = ti * st;
  double ea = exp(zr);
  double Ar = ea * cos(zi), Ai = ea * sin(zi);
  double d = tr * tr + ti * ti;
  double br = ((Ar - 1.0) * tr + Ai * ti) / d;
  double bi = (Ai * tr - (Ar - 1.0) * ti) / d;
  size_t o = (size_t)(p >> 1) * 2048 + (size_t)n * 2 + (p & 1);
  A[o]  = make_float2((float)Ar, (float)Ai);
  Bc[o] = make_float2((float)br, (float)bi);
}

// ---------------------------------------------------------------------------
// K1b: pack conv weights into MFMA-fragment order, split bf16 hi/lo.
// ---------------------------------------------------------------------------
#define NB_PACK (18 * 8 * 64 * 8)    // 73728
#define NC_PACK (54 * 4 * 64 * 8)    // 110592
__global__ __launch_bounds__(256) void k_pack(
    const float* __restrict__ Br, const float* __restrict__ Bi,
    const float* __restrict__ Cr, const float* __restrict__ Ci,
    const float* __restrict__ Dk,
    u16* __restrict__ WBhi, u16* __restrict__ WBlo,
    u16* __restrict__ WChi, u16* __restrict__ WClo) {
  int tid = blockIdx.x * 256 + threadIdx.x;
  if (tid < NB_PACK) {
    int j = tid & 7, lane = (tid >> 3) & 63, nt = (tid >> 9) & 7, kc = tid >> 12;
    int k = kc * 32 + ((lane >> 4) << 3) + j;
    int n = nt * 16 + (lane & 15);
    int tap = k >> 6, c = k & 63;
    float w = (n < 64) ? Br[(tap * 64 + c) * 64 + n]
                       : Bi[(tap * 64 + c) * 64 + (n - 64)];
    u16 hi = f2bf(w);
    WBhi[tid] = hi;
    WBlo[tid] = f2bf(w - bf2f(hi));
  } else {
    int t2 = tid - NB_PACK;
    if (t2 < NC_PACK) {
      int j = t2 & 7, lane = (t2 >> 3) & 63, nt = (t2 >> 9) & 3, kc = t2 >> 11;
      int k = kc * 32 + ((lane >> 4) << 3) + j;     // 0..1727
      int n = nt * 16 + (lane & 15);                 // 0..63
      int s = k / 576, rem = k % 576;
      int tap = rem >> 6, c = rem & 63;
      int widx = (tap * 64 + c) * 64 + n;
      float w = (s == 0) ? 2.f * Cr[widx] : (s == 1) ? -2.f * Ci[widx] : Dk[widx];
      u16 hi = f2bf(w);
      WChi[t2] = hi;
      WClo[t2] = f2bf(w - bf2f(hi));
    }
  }
}

// ---------------------------------------------------------------------------
// K2: convB via MFMA, 4-wave (r1-proven shape), shift-only staging.
// ---------------------------------------------------------------------------
__global__ __launch_bounds__(256) void k_convB_mfma(
    const float* __restrict__ u, const float* __restrict__ x0,
    const u16* __restrict__ WBhi, const u16* __restrict__ WBlo,
    float2* __restrict__ XBUF) {
  __shared__ u16 lhs[6 * 34 * 64];
  __shared__ u16 lls[6 * 34 * 64];
  int img = blockIdx.x, h0 = blockIdx.y * 4;
  int t = threadIdx.x;
  const float* src = (img < NIMG) ? (u + (size_t)img * HWN * NU)
                                  : (x0 + (size_t)(img - NIMG) * HWN * NU);
  // zero halo columns (w=0, w=33): always out-of-range wg, static zero.
  for (int z = t; z < 6 * 2 * 32; z += 256) {
    int col = z & 31, rw = z >> 5;
    int r = rw >> 1, w = (rw & 1) * 33;
    ((u32*)&lhs[(r * 34 + w) * 64])[col] = 0;
    ((u32*)&lls[(r * 34 + w) * 64])[col] = 0;
  }
  // main staging: w = wi+1 (wg = wi in-range), pure-shift indexing.
  for (int idx = t; idx < 6 * 32 * 16; idx += 256) {
    int c4 = idx & 15, wi = (idx >> 4) & 31, r = idx >> 9;
    int hh = h0 - 1 + r;
    float4 v = make_float4(0.f, 0.f, 0.f, 0.f);
    if (hh >= 0 && hh < NH)
      v = *(const float4*)(src + (hh * 32 + wi) * 64 + c4 * 4);
    u16 a0 = f2bf(v.x), a1 = f2bf(v.y), a2 = f2bf(v.z), a3 = f2bf(v.w);
    u16 b0 = f2bf(v.x - bf2f(a0)), b1 = f2bf(v.y - bf2f(a1));
    u16 b2 = f2bf(v.z - bf2f(a2)), b3 = f2bf(v.w - bf2f(a3));
    int w = wi + 1;
    int a = (r * 34 + w) * 64 + (((c4 >> 1) ^ (w & 7)) << 3) + ((c4 & 1) << 2);
    *(ushort4*)&lhs[a] = make_ushort4(a0, a1, a2, a3);
    *(ushort4*)&lls[a] = make_ushort4(b0, b1, b2, b3);
  }
  __syncthreads();
  int lane = t & 63, wv = t >> 6;
  int mgrp = wv >> 1, ng = wv & 1;
  int l15 = lane & 15, l4 = lane >> 4;
  f32x4 acc[4][4];
#pragma unroll
  for (int i = 0; i < 4; i++)
#pragma unroll
    for (int q = 0; q < 4; q++) acc[i][q] = (f32x4){0.f, 0.f, 0.f, 0.f};

  for (int tap = 0; tap < 9; tap++) {
    int kh = tap / 3, kw = tap - kh * 3;
#pragma unroll
    for (int cc = 0; cc < 2; cc++) {
      int kc = tap * 2 + cc;
      bf16x8 ah[4], al[4], wh[4], wl[4];
#pragma unroll
      for (int mti = 0; mti < 4; mti++) {
        int row = mgrp * 2 + (mti >> 1);
        int wt = (mti & 1) * 16 + l15 + kw;
        int off = ((row + kh) * 34 + wt) * 64 + (((cc * 4 + l4) ^ (wt & 7)) << 3);
        ah[mti] = *(const bf16x8*)&lhs[off];
        al[mti] = *(const bf16x8*)&lls[off];
      }
#pragma unroll
      for (int q = 0; q < 4; q++) {
        int nt = ng * 2 + (q & 1) + (q >> 1) * 4;
        size_t woff = ((size_t)((kc * 8 + nt) * 64 + lane)) * 8;
        wh[q] = *(const bf16x8*)&WBhi[woff];
        wl[q] = *(const bf16x8*)&WBlo[woff];
      }
#pragma unroll
      for (int mti = 0; mti < 4; mti++)
#pragma unroll
        for (int q = 0; q < 4; q++) {
          f32x4 c = acc[mti][q];
          c = __builtin_amdgcn_mfma_f32_16x16x32_bf16(ah[mti], wh[q], c, 0, 0, 0);
          c = __builtin_amdgcn_mfma_f32_16x16x32_bf16(ah[mti], wl[q], c, 0, 0, 0);
          c = __builtin_amdgcn_mfma_f32_16x16x32_bf16(al[mti], wh[q], c, 0, 0, 0);
          acc[mti][q] = c;
        }
    }
  }
  float2* dst = XBUF + (size_t)img * IMG_STRIDE;
#pragma unroll
  for (int mti = 0; mti < 4; mti++) {
    int h = h0 + mgrp * 2 + (mti >> 1);
#pragma unroll
    for (int half = 0; half < 2; half++) {
      int p = ng * 32 + half * 16 + l15;
      int pc = p >> 1, pp = p & 1;
#pragma unroll
      for (int reg = 0; reg < 4; reg++) {
        int wpix = (mti & 1) * 16 + l4 * 4 + reg;
        float re = acc[mti][half][reg];
        float im = acc[mti][2 + half][reg];
        int m = (h + wpix + 2) & 3;
        float2 o;
        if (m == 0)      o = make_float2( re,  im);
        else if (m == 1) o = make_float2( im, -re);
        else if (m == 2) o = make_float2(-re, -im);
        else             o = make_float2(-im,  re);
        dst[(size_t)pc * 2048 + (h * 32 + wpix) * 2 + pp] = o;
      }
    }
  }
}

// ---------------------------------------------------------------------------
// K3: forward DST IN-PLACE, register-tiled. Block = (img, pc 0..31).
//     Contiguous 16 KB global window per block.
// ---------------------------------------------------------------------------
__global__ __launch_bounds__(256) void k_dst_fwd(float2* __restrict__ XBUF,
                                                 const float* __restrict__ S) {
  int img = blockIdx.x, pc = blockIdx.y;
  __shared__ float tin[32 * 32 * 4];   // [d1][d2][pp*2+ri]
  __shared__ float t1 [32 * 32 * 4];   // [o1][d2 ^ (ag&7)][ppri]
  int t = threadIdx.x;
  float2* base = XBUF + (size_t)img * IMG_STRIDE + (size_t)pc * 2048;
  for (int n = t; n < 1024; n += 256) {
    float4 v = *(const float4*)&base[n * 2];
    *(float4*)&tin[n * 4] = v;
  }
  __syncthreads();
  {  // stage 1
    int w = t & 31, ag = t >> 5;
    f32x4 acc[4];
#pragma unroll
    for (int i = 0; i < 4; i++) acc[i] = (f32x4){0.f, 0.f, 0.f, 0.f};
#pragma unroll 8
    for (int hh = 0; hh < 32; hh++) {
      f32x4 v = *(const f32x4*)&tin[(hh * 32 + w) * 4];
      f32x4 s4 = *(const f32x4*)&S[hh * 32 + ag * 4];
#pragma unroll
      for (int i = 0; i < 4; i++) acc[i] += s4[i] * v;
    }
    int wp = w ^ (ag & 7);
#pragma unroll
    for (int i = 0; i < 4; i++)
      *(f32x4*)&t1[((ag * 4 + i) * 32 + wp) * 4] = acc[i];
  }
  __syncthreads();
  {  // stage 2
    int pp = t & 1, cg = (t >> 1) & 15, ag = t >> 5;
    float acc[4][2][2];
#pragma unroll
    for (int i = 0; i < 4; i++)
#pragma unroll
      for (int j = 0; j < 2; j++) acc[i][j][0] = acc[i][j][1] = 0.f;
#pragma unroll 8
    for (int w = 0; w < 32; w++) {
      int wp = w ^ (ag & 7);
      float2 sc = *(const float2*)&S[w * 32 + cg * 2];
#pragma unroll
      for (int i = 0; i < 4; i++) {
        float2 tv = *(const float2*)&t1[((ag * 4 + i) * 32 + wp) * 4 + pp * 2];
        acc[i][0][0] = fmaf(tv.x, sc.x, acc[i][0][0]);
        acc[i][0][1] = fmaf(tv.y, sc.x, acc[i][0][1]);
        acc[i][1][0] = fmaf(tv.x, sc.y, acc[i][1][0]);
        acc[i][1][1] = fmaf(tv.y, sc.y, acc[i][1][1]);
      }
    }
#pragma unroll
    for (int i = 0; i < 4; i++)
#pragma unroll
      for (int j = 0; j < 2; j++) {
        int n = (ag * 4 + i) * 32 + cg * 2 + j;
        base[n * 2 + pp] = make_float2(acc[i][j][0], acc[i][j][1]);
      }
  }
}

// ---------------------------------------------------------------------------
// K4: scan over l. Linear-offset streaming; unroll 4 so the compiler can
//     batch the independent per-step loads ahead of the serial compute chain.
// ---------------------------------------------------------------------------
__global__ __launch_bounds__(256) void k_scan(const float2* __restrict__ A,
                                              const float2* __restrict__ Bc,
                                              float2* __restrict__ X) {
  int gx = blockIdx.x;
  int b = gx >> 8, sl = gx & 255;
  int t = threadIdx.x;
  size_t off = (size_t)sl * 256 + t;
  float2 Av = A[off];
  float2 Bv = Bc[off];
  float2 v0 = X[(size_t)(NIMG + b) * IMG_STRIDE + off];
  float2 x;
  x.x = Bv.x * v0.x - Bv.y * v0.y;
  x.y = Bv.x * v0.y + Bv.y * v0.x;
#pragma unroll 4
  for (int l = 0; l < NL; l++) {
    size_t idx = (size_t)(l * NB + b) * IMG_STRIDE + off;
    float2 v = X[idx];
    float vr = Bv.x * v.x - Bv.y * v.y;
    float vi = Bv.x * v.y + Bv.y * v.x;
    float2 nx;
    nx.x = Av.x * x.x - Av.y * x.y + vr;
    nx.y = Av.x * x.y + Av.y * x.x + vi;
    x = nx;
    X[idx] = x;
  }
}

// ---------------------------------------------------------------------------
// K5: inverse DST IN-PLACE, register-tiled, + phase + bf16-split pack.
//     Reads contiguous 16 KB; writes the SAME 16 KB window as packed u32:
//     XP[pc][pix][{re_pp0, re_pp1, im_pp0, im_pp1}], each hi | lo<<16.
// ---------------------------------------------------------------------------
__global__ __launch_bounds__(256) void k_dst_inv(float2* __restrict__ XBUF,
                                                 const float* __restrict__ S) {
  int img = blockIdx.x, pc = blockIdx.y;
  __shared__ float tin[32 * 32 * 4];   // [a][c][ppri]
  __shared__ float t1 [32 * 32 * 4];   // [h][c ^ (ag&7)][ppri]
  int t = threadIdx.x;
  float2* base = XBUF + (size_t)img * IMG_STRIDE + (size_t)pc * 2048;
  for (int n = t; n < 1024; n += 256) {
    float4 v = *(const float4*)&base[n * 2];
    *(float4*)&tin[n * 4] = v;
  }
  __syncthreads();
  {  // stage 1: t1[h][c] = sum_a S[h][a] * xin[a][c]
    int c = t & 31, ag = t >> 5;
    f32x4 acc[4];
#pragma unroll
    for (int i = 0; i < 4; i++) acc[i] = (f32x4){0.f, 0.f, 0.f, 0.f};
#pragma unroll 8
    for (int a = 0; a < 32; a++) {
      f32x4 v = *(const f32x4*)&tin[(a * 32 + c) * 4];
      f32x4 s4 = *(const f32x4*)&S[a * 32 + ag * 4];
#pragma unroll
      for (int i = 0; i < 4; i++) acc[i] += s4[i] * v;
    }
    int cp = c ^ (ag & 7);
#pragma unroll
    for (int i = 0; i < 4; i++)
      *(f32x4*)&t1[((ag * 4 + i) * 32 + cp) * 4] = acc[i];
  }
  __syncthreads();
  {  // stage 2: out[h][w] = sum_c S[w][c] * t1[h][c]; phase; split-pack
    int pp = t & 1, wg = (t >> 1) & 15, ag = t >> 5;
    float acc[4][2][2];
#pragma unroll
    for (int i = 0; i < 4; i++)
#pragma unroll
      for (int j = 0; j < 2; j++) acc[i][j][0] = acc[i][j][1] = 0.f;
#pragma unroll 8
    for (int c = 0; c < 32; c++) {
      int cp = c ^ (ag & 7);
      float2 sc = *(const float2*)&S[c * 32 + wg * 2];
#pragma unroll
      for (int i = 0; i < 4; i++) {
        float2 tv = *(const float2*)&t1[((ag * 4 + i) * 32 + cp) * 4 + pp * 2];
        acc[i][0][0] = fmaf(tv.x, sc.x, acc[i][0][0]);
        acc[i][0][1] = fmaf(tv.y, sc.x, acc[i][0][1]);
        acc[i][1][0] = fmaf(tv.x, sc.y, acc[i][1][0]);
        acc[i][1][1] = fmaf(tv.y, sc.y, acc[i][1][1]);
      }
    }
    u32* gw = (u32*)(XBUF + (size_t)img * IMG_STRIDE) + (size_t)pc * 4096;
#pragma unroll
    for (int i = 0; i < 4; i++)
#pragma unroll
      for (int j = 0; j < 2; j++) {
        int h = ag * 4 + i, wpx = wg * 2 + j;
        float re = acc[i][j][0], im = acc[i][j][1];
        int m = (h + wpx + 2) & 3;
        float2 o;
        if (m == 0)      o = make_float2( re,  im);
        else if (m == 1) o = make_float2(-im,  re);
        else if (m == 2) o = make_float2(-re, -im);
        else             o = make_float2( im, -re);
        u16 hr = f2bf(o.x), lr = f2bf(o.x - bf2f(hr));
        u16 hm = f2bf(o.y), lm = f2bf(o.y - bf2f(hm));
        int pix = h * 32 + wpx;
        gw[pix * 4 + pp]     = (u32)hr | ((u32)lr << 16);   // comp 0 (re)
        gw[pix * 4 + 2 + pp] = (u32)hm | ((u32)lm << 16);   // comp 1 (im)
      }
  }
}

// ---------------------------------------------------------------------------
// K6: convCD via MFMA + gelu, 4-wave (r1-proven shape), shift-only staging,
//     halo columns zeroed once per block (invariant across all 3 s phases).
// ---------------------------------------------------------------------------
__global__ __launch_bounds__(256) void k_convCD_mfma(
    const u32* __restrict__ XP,      // XBUF viewed as packed slots
    const float* __restrict__ u,
    const u16* __restrict__ WChi, const u16* __restrict__ WClo,
    float* __restrict__ out) {
  __shared__ u16 lhs[6 * 34 * 64];
  __shared__ u16 lls[6 * 34 * 64];
  int img = blockIdx.x, h0 = blockIdx.y * 4;
  int t = threadIdx.x;
  int lane = t & 63, wv = t >> 6;
  int mgrp = wv >> 1, ng = wv & 1;
  int l15 = lane & 15, l4 = lane >> 4;
  const u32* xim = XP + (size_t)img * IMG_STRIDE * 2;   // 131072 u32 per image
  const float* uim = u + (size_t)img * HWN * NU;
  f32x4 acc[4][2];
#pragma unroll
  for (int i = 0; i < 4; i++) {
    acc[i][0] = (f32x4){0.f, 0.f, 0.f, 0.f};
    acc[i][1] = (f32x4){0.f, 0.f, 0.f, 0.f};
  }
  // zero halo columns once: w=0 / w=33 stay zero for all phases.
  for (int z = t; z < 6 * 2 * 32; z += 256) {
    int col = z & 31, rw = z >> 5;
    int r = rw >> 1, w = (rw & 1) * 33;
    ((u32*)&lhs[(r * 34 + w) * 64])[col] = 0;
    ((u32*)&lls[(r * 34 + w) * 64])[col] = 0;
  }

  for (int s = 0; s < 3; s++) {
    __syncthreads();
    if (s < 2) {
      // comp s: per (pc, pixel) load uint2 {pp0, pp1}; wi innermost for
      // coalescing; shift-only indexing (main region w=wi+1).
      for (int idx = t; idx < 6 * 32 * 32; idx += 256) {
        int wi = idx & 31, pc = (idx >> 5) & 31, r = idx >> 10;
        int hh = h0 - 1 + r;
        uint2 d = make_uint2(0u, 0u);
        if (hh >= 0 && hh < NH)
          d = *(const uint2*)(xim + (size_t)pc * 4096 + (hh * 32 + wi) * 4 + s * 2);
        u32 hip = (d.x & 0xffffu) | (d.y << 16);
        u32 lop = (d.x >> 16) | (d.y & 0xffff0000u);
        int w = wi + 1;
        int c = pc * 2;                               // channel pair c, c+1
        int a = (r * 34 + w) * 64 + (((c >> 3) ^ (w & 7)) << 3) + (c & 7);
        *(u32*)&lhs[a] = hip;
        *(u32*)&lls[a] = lop;
      }
    } else {
      for (int idx = t; idx < 6 * 32 * 16; idx += 256) {
        int c4 = idx & 15, wi = (idx >> 4) & 31, r = idx >> 9;
        int hh = h0 - 1 + r;
        float4 v = make_float4(0.f, 0.f, 0.f, 0.f);
        if (hh >= 0 && hh < NH)
          v = *(const float4*)(uim + (hh * 32 + wi) * 64 + c4 * 4);
        u16 a0 = f2bf(v.x), a1 = f2bf(v.y), a2 = f2bf(v.z), a3 = f2bf(v.w);
        u16 b0 = f2bf(v.x - bf2f(a0)), b1 = f2bf(v.y - bf2f(a1));
        u16 b2 = f2bf(v.z - bf2f(a2)), b3 = f2bf(v.w - bf2f(a3));
        int w = wi + 1;
        int a = (r * 34 + w) * 64 + (((c4 >> 1) ^ (w & 7)) << 3) + ((c4 & 1) << 2);
        *(ushort4*)&lhs[a] = make_ushort4(a0, a1, a2, a3);
        *(ushort4*)&lls[a] = make_ushort4(b0, b1, b2, b3);
      }
    }
    __syncthreads();
    for (int tap = 0; tap < 9; tap++) {
      int kh = tap / 3, kw = tap - kh * 3;
#pragma unroll
      for (int cc = 0; cc < 2; cc++) {
        int kc = (s * 9 + tap) * 2 + cc;
        bf16x8 ah[4], al[4], wh[2], wl[2];
#pragma unroll
        for (int mti = 0; mti < 4; mti++) {
          int row = mgrp * 2 + (mti >> 1);
          int wt = (mti & 1) * 16 + l15 + kw;
          int off = ((row + kh) * 34 + wt) * 64 + (((cc * 4 + l4) ^ (wt & 7)) << 3);
          ah[mti] = *(const bf16x8*)&lhs[off];
          al[mti] = *(const bf16x8*)&lls[off];
        }
#pragma unroll
        for (int q = 0; q < 2; q++) {
          int nt = ng * 2 + q;
          size_t woff = ((size_t)((kc * 4 + nt) * 64 + lane)) * 8;
          wh[q] = *(const bf16x8*)&WChi[woff];
          wl[q] = *(const bf16x8*)&WClo[woff];
        }
#pragma unroll
        for (int mti = 0; mti < 4; mti++)
#pragma unroll
          for (int q = 0; q < 2; q++) {
            f32x4 c = acc[mti][q];
            c = __builtin_amdgcn_mfma_f32_16x16x32_bf16(ah[mti], wh[q], c, 0, 0, 0);
            c = __builtin_amdgcn_mfma_f32_16x16x32_bf16(ah[mti], wl[q], c, 0, 0, 0);
            c = __builtin_amdgcn_mfma_f32_16x16x32_bf16(al[mti], wh[q], c, 0, 0, 0);
            acc[mti][q] = c;
          }
      }
    }
  }
  float* dst = out + (size_t)img * HWN * NU;
#pragma unroll
  for (int mti = 0; mti < 4; mti++) {
    int h = h0 + mgrp * 2 + (mti >> 1);
#pragma unroll
    for (int q = 0; q < 2; q++) {
      int un = (ng * 2 + q) * 16 + l15;
#pragma unroll
      for (int reg = 0; reg < 4; reg++) {
        int wpix = (mti & 1) * 16 + l4 * 4 + reg;
        float x = acc[mti][q][reg];
        float z = 0.7978845608028654f * (x + 0.044715f * x * x * x);
        float e = __expf(2.f * z);
        float th = 1.f - 2.f / (e + 1.f);
        dst[(h * 32 + wpix) * 64 + un] = 0.5f * x * (1.f + th);
      }
    }
  }
}

// ---------------------------------------------------------------------------
extern "C" void kernel_launch(void* const* d_in, const int* in_sizes, int n_in,
                              void* d_out, int out_size, void* d_ws, size_t ws_size,
                              hipStream_t stream) {
  const float* u        = (const float*)d_in[0];
  const float* x0       = (const float*)d_in[1];
  const float* Lre      = (const float*)d_in[2];
  const float* Lim      = (const float*)d_in[3];
  const float* values   = (const float*)d_in[4];
  const float* log_step = (const float*)d_in[5];
  const float* Br       = (const float*)d_in[6];
  const float* Bi       = (const float*)d_in[7];
  const float* Cr       = (const float*)d_in[8];
  const float* Ci       = (const float*)d_in[9];
  const float* Dk       = (const float*)d_in[10];
  float* out = (float*)d_out;

  char* ws = (char*)d_ws;
  float*  S    = (float*)ws;                       ws += 4096;
  float*  kv   = (float*)ws;                       ws += 4096;
  float2* A    = (float2*)ws;                      ws += 524288;
  float2* Bc   = (float2*)ws;                      ws += 524288;
  u16*    WBhi = (u16*)ws;                         ws += NB_PACK * 2;
  u16*    WBlo = (u16*)ws;                         ws += NB_PACK * 2;
  u16*    WChi = (u16*)ws;                         ws += NC_PACK * 2;
  u16*    WClo = (u16*)ws;                         ws += NC_PACK * 2;
  float2* XBUF = (float2*)ws;

  hipLaunchKernelGGL(k_setup,      dim3(1),            dim3(1024), 0, stream, values, S, kv);
  hipLaunchKernelGGL(k_coeff,      dim3(256),          dim3(256),  0, stream, Lre, Lim, log_step, kv, A, Bc);
  hipLaunchKernelGGL(k_pack,       dim3(720),          dim3(256),  0, stream, Br, Bi, Cr, Ci, Dk, WBhi, WBlo, WChi, WClo);
  hipLaunchKernelGGL(k_convB_mfma, dim3(NIMG_TOT, 8),  dim3(256),  0, stream, u, x0, WBhi, WBlo, XBUF);
  hipLaunchKernelGGL(k_dst_fwd,    dim3(NIMG_TOT, 32), dim3(256),  0, stream, XBUF, S);
  hipLaunchKernelGGL(k_scan,       dim3(2048),         dim3(256),  0, stream, A, Bc, XBUF);
  hipLaunchKernelGGL(k_dst_inv,    dim3(NIMG, 32),     dim3(256),  0, stream, XBUF, S);
  hipLaunchKernelGGL(k_convCD_mfma,dim3(NIMG, 8),      dim3(256),  0, stream, (const u32*)XBUF, u, WChi, WClo, out);
}